// Round 3
// baseline (671.688 us; speedup 1.0000x reference)
//
#include <hip/hip_runtime.h>

// MultiHeadedAttention cross-attention pipeline for MI355X (gfx950).
// B=32, N_img=576, L_q=256, D=1024, H=16, dk=64.
// Pipeline: cvt fp32->bf16 -> merged QKV proj GEMM (bf16 MFMA) -> merged flash
// attention -> merged output proj GEMM (fp32 out). 2% absmax tol allows bf16.
//
// R7: faithful m201 8-phase schedule (fixing R6's three deviations):
//   - stages spread ~1 half-tile per phase: P1: B(t+1)h1, P3: A(t+2)h0,
//     P4: A(t+2)h1+B(t+2)h0 (legal: each wave reads only its own A/B half;
//     A(t) reads complete by P2-end, B(t) by P3-end, anchored by the
//     lgkmcnt(0) pinned between each phase's two barriers)
//   - NO sched_barrier(0) (m141: order-pinning regressed to 510 TF);
//     correctness needs only volatile-asm ordering vs s_barrier
//   - vmcnt(6) at P4 only: drains B(t+1)h1, leaves tile t+2's 3 staged
//     halves (6 loads) in flight across the barrier; vmcnt(0) only at t=14
// Ledger (per-wave, 2 loads/half-tile): steady outstanding at P4 = 8
// {B(t+1)h1, A(t+2)h0, A(t+2)h1, B(t+2)h0}; vmcnt(6) keeps the newest 6.
// Prologue: T0 all 4 halves + T1 {Ah0,Ah1,Bh0}; vmcnt(6) -> T0 ready.

typedef __bf16 bf16;
typedef __attribute__((ext_vector_type(8))) __bf16 bf16x8;
typedef __attribute__((ext_vector_type(4))) __bf16 bf16x4;
typedef __attribute__((ext_vector_type(2))) __bf16 bf16x2;
typedef __attribute__((ext_vector_type(4))) float f32x4;

__device__ __forceinline__ void g2lds16(const void* g, void* l) {
  // async global->LDS, 16B/lane; LDS dest = wave-uniform base + lane*16
  __builtin_amdgcn_global_load_lds((const __attribute__((address_space(1))) void*)g,
                                   (__attribute__((address_space(3))) void*)l,
                                   16, 0, 0);
}

// ---------------------------------------------------------------------------
// fp32 -> bf16 conversion, all 5 tensors in one launch (float4 in, bf16x4 out)
// ---------------------------------------------------------------------------
__global__ void cvt_bf16_multi(const float* s0, bf16* d0, int n0,
                               const float* s1, bf16* d1, int n1,
                               const float* s2, bf16* d2, int n2,
                               const float* s3, bf16* d3, int n3,
                               const float* s4, bf16* d4, int n4c) {
  const int total = n0 + n1 + n2 + n3 + n4c;
  const int stride = gridDim.x * blockDim.x;
  for (int i = blockIdx.x * blockDim.x + threadIdx.x; i < total; i += stride) {
    int j = i;
    const float* s; bf16* d;
    if (j < n0) { s = s0; d = d0; }
    else { j -= n0;
      if (j < n1) { s = s1; d = d1; }
      else { j -= n1;
        if (j < n2) { s = s2; d = d2; }
        else { j -= n2;
          if (j < n3) { s = s3; d = d3; }
          else { j -= n3; s = s4; d = d4; }
        }
      }
    }
    const float4 v = ((const float4*)s)[j];
    bf16x4 o = {(bf16)v.x, (bf16)v.y, (bf16)v.z, (bf16)v.w};
    ((bf16x4*)d)[j] = o;
  }
}

// ---------------------------------------------------------------------------
// NT GEMM: C[m,e] = sum_d A[m,d]*W[e,d] + bias[e].  K=1024 fixed (16 tiles).
// BM=BN=256, BK=64, 512 thr = 8 waves (2Mx4N), wave tile 128x64.
// Two independent problems merged on blockIdx.y (ySplit boundary).
// LDS XOR-swizzled: slot (row, s) holds global k-chunk s^(row&7); 0 conflicts.
// MODE 0: proj epilogue -> bf16 head-split [p][B,H,L,64]; p==2 (V) transposed
//         to [B,H,64,L]. Lrow = L (576 or 256), N = 3072.
// MODE 1: final proj -> fp32 out[m*1024 + e], N = 1024.
// ---------------------------------------------------------------------------
template <int MODE>
__global__ __launch_bounds__(512, 2)
void gemm_bt(const bf16* __restrict__ A0, const bf16* __restrict__ W0,
             const float* __restrict__ bi0, void* __restrict__ o0, int L0,
             const bf16* __restrict__ A1, const bf16* __restrict__ W1,
             const float* __restrict__ bi1, void* __restrict__ o1, int L1,
             int ySplit) {
  __shared__ alignas(16) bf16 As[2][256 * 64];
  __shared__ alignas(16) bf16 Bs[2][256 * 64];
  const int tid = threadIdx.x;
  const int w = tid >> 6, lane = tid & 63;
  const int lr = lane & 15, quad = lane >> 4, i_q4 = quad * 4;
  const int wm = w >> 2, wn = w & 3;
  const int wr = wm * 128, wc = wn * 64;  // wave tile origin (128x64)

  const bf16* A; const bf16* Bw; const float* bias; void* outp; int Lrow;
  int my = (int)blockIdx.y;
  if (my < ySplit) { A = A0; Bw = W0; bias = bi0; outp = o0; Lrow = L0; }
  else { my -= ySplit; A = A1; Bw = W1; bias = bi1; outp = o1; Lrow = L1; }
  const int mBase = my * 256, nBase = (int)blockIdx.x * 256;

  // staging: lane fetches global chunk (lane&7)^(row&7) so LDS ends up
  // swizzled; row = rowBase + (lane>>3), rowBase % 8 == 0 always.
  const int swl = (((lane & 7) ^ ((lane >> 3) & 7)) * 8);
  const bf16* Ab = A + (size_t)(mBase + (lane >> 3)) * 1024 + swl;
  const bf16* Bb = Bw + (size_t)(nBase + (lane >> 3)) * 1024 + swl;

  // stage one 128-row half (2 g2lds/wave = 2 vmcnt ticks) of A or B, tile kt
  auto stA = [&](int kt, int half) {
    const int s = kt & 1, k0 = kt * 64;
#pragma unroll
    for (int c = 0; c < 2; ++c) {
      const int r = half * 128 + c * 64 + w * 8;   // wave-uniform, %8==0
      g2lds16(Ab + (size_t)r * 1024 + k0, &As[s][r * 64]);
    }
  };
  auto stB = [&](int kt, int half) {
    const int s = kt & 1, k0 = kt * 64;
#pragma unroll
    for (int c = 0; c < 2; ++c) {
      const int r = half * 128 + c * 64 + w * 8;
      g2lds16(Bb + (size_t)r * 1024 + k0, &Bs[s][r * 64]);
    }
  };

  f32x4 acc[8][4] = {};

  // prologue: T0 {Ah0,Ah1,Bh0,Bh1} + T1 {Ah0,Ah1,Bh0}; T1 Bh1 comes at P1.
  stA(0, 0); stA(0, 1); stB(0, 0); stB(0, 1);
  stA(1, 0); stA(1, 1); stB(1, 0);
  asm volatile("s_waitcnt vmcnt(6)" ::: "memory");  // T0 ready, T1x3 in flight
  __builtin_amdgcn_s_barrier();

  const int so0 = (quad ^ (lr & 7)) * 8;        // k-slice 0 swizzled slot
  const int so1 = ((quad | 4) ^ (lr & 7)) * 8;  // k-slice 1

  bf16x8 a[8][2], b[4][2];
#pragma unroll 2
  for (int t = 0; t < 16; ++t) {
    const bf16* Asb = As[t & 1];
    const bf16* Bsb = Bs[t & 1];
    // ---- P1: read a[0..3]+b[0..1] (12); stage B(t+1)h1; MFMA Q0 ----
#pragma unroll
    for (int i = 0; i < 4; ++i) {
      const bf16* p = Asb + (wr + i * 16 + lr) * 64;
      a[i][0] = *(const bf16x8*)(p + so0);
      a[i][1] = *(const bf16x8*)(p + so1);
    }
#pragma unroll
    for (int j = 0; j < 2; ++j) {
      const bf16* p = Bsb + (wc + j * 16 + lr) * 64;
      b[j][0] = *(const bf16x8*)(p + so0);
      b[j][1] = *(const bf16x8*)(p + so1);
    }
    if (t + 1 < 16) stB(t + 1, 1);
    asm volatile("s_waitcnt lgkmcnt(8)" ::: "memory");
    __builtin_amdgcn_s_barrier();
    asm volatile("s_waitcnt lgkmcnt(0)" ::: "memory");
    __builtin_amdgcn_s_setprio(1);
#pragma unroll
    for (int ks = 0; ks < 2; ++ks)
#pragma unroll
      for (int i = 0; i < 4; ++i)
#pragma unroll
        for (int j = 0; j < 2; ++j)
          acc[i][j] = __builtin_amdgcn_mfma_f32_16x16x32_bf16(a[i][ks], b[j][ks], acc[i][j], 0, 0, 0);
    __builtin_amdgcn_s_setprio(0);
    __builtin_amdgcn_s_barrier();
    // ---- P2: read a[4..7] (8); MFMA Q1 ----
#pragma unroll
    for (int i = 4; i < 8; ++i) {
      const bf16* p = Asb + (wr + i * 16 + lr) * 64;
      a[i][0] = *(const bf16x8*)(p + so0);
      a[i][1] = *(const bf16x8*)(p + so1);
    }
    __builtin_amdgcn_s_barrier();
    asm volatile("s_waitcnt lgkmcnt(0)" ::: "memory");
    __builtin_amdgcn_s_setprio(1);
#pragma unroll
    for (int ks = 0; ks < 2; ++ks)
#pragma unroll
      for (int i = 4; i < 8; ++i)
#pragma unroll
        for (int j = 0; j < 2; ++j)
          acc[i][j] = __builtin_amdgcn_mfma_f32_16x16x32_bf16(a[i][ks], b[j][ks], acc[i][j], 0, 0, 0);
    __builtin_amdgcn_s_setprio(0);
    __builtin_amdgcn_s_barrier();
    // ---- P3: read b[2..3] (4); stage A(t+2)h0; MFMA Q2 ----
#pragma unroll
    for (int j = 2; j < 4; ++j) {
      const bf16* p = Bsb + (wc + j * 16 + lr) * 64;
      b[j][0] = *(const bf16x8*)(p + so0);
      b[j][1] = *(const bf16x8*)(p + so1);
    }
    if (t + 2 < 16) stA(t + 2, 0);
    __builtin_amdgcn_s_barrier();
    asm volatile("s_waitcnt lgkmcnt(0)" ::: "memory");
    __builtin_amdgcn_s_setprio(1);
#pragma unroll
    for (int ks = 0; ks < 2; ++ks)
#pragma unroll
      for (int i = 0; i < 4; ++i)
#pragma unroll
        for (int j = 2; j < 4; ++j)
          acc[i][j] = __builtin_amdgcn_mfma_f32_16x16x32_bf16(a[i][ks], b[j][ks], acc[i][j], 0, 0, 0);
    __builtin_amdgcn_s_setprio(0);
    __builtin_amdgcn_s_barrier();
    // ---- P4: stage A(t+2)h1 + B(t+2)h0; MFMA Q3; counted vmcnt ----
    if (t + 2 < 16) { stA(t + 2, 1); stB(t + 2, 0); }
    __builtin_amdgcn_s_barrier();
    __builtin_amdgcn_s_setprio(1);
#pragma unroll
    for (int ks = 0; ks < 2; ++ks)
#pragma unroll
      for (int i = 4; i < 8; ++i)
#pragma unroll
        for (int j = 2; j < 4; ++j)
          acc[i][j] = __builtin_amdgcn_mfma_f32_16x16x32_bf16(a[i][ks], b[j][ks], acc[i][j], 0, 0, 0);
    __builtin_amdgcn_s_setprio(0);
    // drain through B(t+1)h1 (t+1 fully staged); keep tile t+2's 6 in flight
    if (t < 14) {
      asm volatile("s_waitcnt vmcnt(6)" ::: "memory");
    } else if (t == 14) {
      asm volatile("s_waitcnt vmcnt(0)" ::: "memory");
    }
    __builtin_amdgcn_s_barrier();
  }

  // epilogue. C/D layout: col = lane&15, row = quad*4 + reg  [m89-verified]
  if constexpr (MODE == 1) {
    float* out = (float*)outp;
#pragma unroll
    for (int j = 0; j < 4; ++j) {
      const int e = nBase + wc + j * 16 + lr;
      const float bv = bias[e];
#pragma unroll
      for (int i = 0; i < 8; ++i) {
        const int mb = mBase + wr + i * 16 + i_q4;
#pragma unroll
        for (int r = 0; r < 4; ++r)
          out[(size_t)(mb + r) * 1024 + e] = acc[i][j][r] + bv;
      }
    }
  } else {
    bf16* out = (bf16*)outp;
    const int L = Lrow;
    const size_t slab = (size_t)512 * L * 64;  // one of iq/ik/iv
    int bb[8], ll[8];
#pragma unroll
    for (int i = 0; i < 8; ++i) {
      const int m = mBase + wr + i * 16 + i_q4;  // 4 consecutive rows share b (L%4==0)
      bb[i] = m / L;
      ll[i] = m - bb[i] * L;
    }
#pragma unroll
    for (int j = 0; j < 4; ++j) {
      const int eb = nBase + wc + j * 16;       // 16-aligned: p,h uniform per tile
      const int p = eb >> 10, h = (eb >> 6) & 15, d = (eb & 63) + lr;
      const float bv = bias[eb + lr];
      if (p < 2) {  // q/k: [B,H,L,64]
        bf16* o2 = out + (size_t)p * slab;
#pragma unroll
        for (int i = 0; i < 8; ++i) {
          bf16* o3 = o2 + ((size_t)(bb[i] * 16 + h) * L + ll[i]) * 64 + d;
#pragma unroll
          for (int r = 0; r < 4; ++r) o3[r * 64] = (bf16)(acc[i][j][r] + bv);
        }
      } else {      // v: transposed [B,H,64,L] so PV B-frag is contiguous
        bf16* o2 = out + 2 * slab;
#pragma unroll
        for (int i = 0; i < 8; ++i) {
          bf16x4 v;
#pragma unroll
          for (int r = 0; r < 4; ++r) v[r] = (bf16)(acc[i][j][r] + bv);
          *(bf16x4*)(o2 + ((size_t)(bb[i] * 16 + h) * 64 + d) * L + ll[i]) = v;
        }
      }
    }
  }
}

// ---------------------------------------------------------------------------
// Attention (two problems merged on blockIdx.x; xSplit boundary).
// Q:[B,H,Lq,64] K:[B,H,Lk,64] Vt:[B,H,64,Lk] (bf16), mask:[B,Lk] int
// (0 = masked), out:[B,Lq,H*64] bf16. 1 wave = 32 queries; K-tiles of 32.
// Fixed-shift softmax: p = exp2(s*log2e/8 + mb); masked keys mb=-1e9 -> p=0.
// Key->lane map interleaved (key = 2*lr + jn) so p-pairs pack to b32 writes.
// ---------------------------------------------------------------------------
#define PSTR 40
__global__ __launch_bounds__(256)
void attn(const bf16* __restrict__ Q0, const bf16* __restrict__ K0,
          const bf16* __restrict__ V0, const int* __restrict__ mk0,
          bf16* __restrict__ ou0, int Lq0, int Lk0, int xSplit,
          const bf16* __restrict__ Q1, const bf16* __restrict__ K1,
          const bf16* __restrict__ V1, const int* __restrict__ mk1,
          bf16* __restrict__ ou1, int Lq1, int Lk1) {
  __shared__ float mk[576];
  __shared__ alignas(16) bf16 pb[4][2][2][16 * PSTR];
  const int tid = threadIdx.x;
  const int w = tid >> 6, lane = tid & 63;
  const int lr = lane & 15, quad = lane >> 4, i_q4 = quad * 4;
  const int bh = blockIdx.y, b = bh >> 4, h = bh & 15;

  const bf16* Q; const bf16* K; const bf16* Vt; const int* mask; bf16* out;
  int Lq, Lk, gx = (int)blockIdx.x;
  if (gx < xSplit) { Q = Q0; K = K0; Vt = V0; mask = mk0; out = ou0; Lq = Lq0; Lk = Lk0; }
  else { gx -= xSplit; Q = Q1; K = K1; Vt = V1; mask = mk1; out = ou1; Lq = Lq1; Lk = Lk1; }
  const int q0 = gx * 128 + w * 32;

  for (int k = tid; k < Lk; k += 256)
    mk[k] = (mask[b * Lk + k] == 0) ? -1e9f : 0.0f;
  __syncthreads();
  if (q0 >= Lq) return;  // tail strips: whole idle waves (Lq % 32 == 0)

  // Q A-fragments: 2 m-tiles x 2 k-halves, held for the whole K loop
  bf16x8 qa[2][2];
#pragma unroll
  for (int i = 0; i < 2; ++i) {
    const bf16* Qb = Q + ((size_t)bh * Lq + q0 + i * 16 + lr) * 64 + quad * 8;
    qa[i][0] = *(const bf16x8*)(Qb);
    qa[i][1] = *(const bf16x8*)(Qb + 32);
  }
  const bf16* Kb = K + (size_t)bh * Lk * 64;
  const bf16* Vb = Vt + (size_t)bh * 64 * Lk;

  // K B-frag: key = kt*32 + 2*lr + jn (interleaved); V B-frag: k = quad*8+jj
  bf16x8 kc[2][2], kn[2][2], vc[4], vn[4];
  {
    const bf16* kp = Kb + (size_t)(lr * 2) * 64 + quad * 8;
    kc[0][0] = *(const bf16x8*)(kp);       kc[0][1] = *(const bf16x8*)(kp + 32);
    kc[1][0] = *(const bf16x8*)(kp + 64);  kc[1][1] = *(const bf16x8*)(kp + 96);
    const bf16* vp = Vb + quad * 8;
#pragma unroll
    for (int j = 0; j < 4; ++j) vc[j] = *(const bf16x8*)(vp + (size_t)(j * 16 + lr) * Lk);
  }

  f32x4 o[2][4] = {};
  float ls[2][4] = {};
  const int nkt = Lk >> 5;
  constexpr float SCL = 0.18033688f;  // log2(e)/8  (1/sqrt(dk) folded)
#pragma unroll 2
  for (int kt = 0; kt < nkt; ++kt) {
    // prefetch next tile (clamped; avoids reading past the slab)
    const int kp1 = (kt + 1 < nkt) ? kt + 1 : kt;
    {
      const bf16* kp = Kb + ((size_t)kp1 * 32 + lr * 2) * 64 + quad * 8;
      kn[0][0] = *(const bf16x8*)(kp);       kn[0][1] = *(const bf16x8*)(kp + 32);
      kn[1][0] = *(const bf16x8*)(kp + 64);  kn[1][1] = *(const bf16x8*)(kp + 96);
      const bf16* vp = Vb + kp1 * 32 + quad * 8;
#pragma unroll
      for (int j = 0; j < 4; ++j) vn[j] = *(const bf16x8*)(vp + (size_t)(j * 16 + lr) * Lk);
    }

    // scores: c[i][jn], C-layout col=lr -> key = kt*32 + 2*lr + jn
    f32x4 c[2][2];
#pragma unroll
    for (int i = 0; i < 2; ++i)
#pragma unroll
      for (int jn = 0; jn < 2; ++jn) {
        const f32x4 z = {};
        c[i][jn] = __builtin_amdgcn_mfma_f32_16x16x32_bf16(qa[i][0], kc[jn][0], z, 0, 0, 0);
        c[i][jn] = __builtin_amdgcn_mfma_f32_16x16x32_bf16(qa[i][1], kc[jn][1], c[i][jn], 0, 0, 0);
      }

    const float m0 = mk[kt * 32 + lr * 2], m1 = mk[kt * 32 + lr * 2 + 1];
#pragma unroll
    for (int i = 0; i < 2; ++i) {
      bf16* pw = &pb[w][kt & 1][i][0];
#pragma unroll
      for (int r = 0; r < 4; ++r) {
        const float p0 = __builtin_amdgcn_exp2f(__builtin_fmaf(c[i][0][r], SCL, m0));
        const float p1 = __builtin_amdgcn_exp2f(__builtin_fmaf(c[i][1][r], SCL, m1));
        ls[i][r] += p0 + p1;
        bf16x2 pp = {(bf16)p0, (bf16)p1};
        *(bf16x2*)(pw + (i_q4 + r) * PSTR + lr * 2) = pp;
      }
    }
    // P A-frag: P[m=lr][k=quad*8+jj], LDS col == key offset (interleaved map)
#pragma unroll
    for (int i = 0; i < 2; ++i) {
      const bf16x8 pa = *(const bf16x8*)(&pb[w][kt & 1][i][0] + lr * PSTR + quad * 8);
#pragma unroll
      for (int j = 0; j < 4; ++j)
        o[i][j] = __builtin_amdgcn_mfma_f32_16x16x32_bf16(pa, vc[j], o[i][j], 0, 0, 0);
    }
#pragma unroll
    for (int jn = 0; jn < 2; ++jn)
#pragma unroll
      for (int kh = 0; kh < 2; ++kh) kc[jn][kh] = kn[jn][kh];
#pragma unroll
    for (int j = 0; j < 4; ++j) vc[j] = vn[j];
  }

  // deferred l reduction (16 lanes of each quad hold disjoint key partials)
  float inv[2][4];
#pragma unroll
  for (int i = 0; i < 2; ++i)
#pragma unroll
    for (int r = 0; r < 4; ++r) {
      float s = ls[i][r];
#pragma unroll
      for (int off = 1; off < 16; off <<= 1) s += __shfl_xor(s, off);
      inv[i][r] = 1.0f / s;
    }

#pragma unroll
  for (int i = 0; i < 2; ++i) {
    bf16* ob = out + ((size_t)b * Lq + q0 + i * 16 + i_q4) * 1024 + h * 64;
#pragma unroll
    for (int j = 0; j < 4; ++j)
#pragma unroll
      for (int r = 0; r < 4; ++r)
        ob[(size_t)r * 1024 + j * 16 + lr] = (bf16)(o[i][j][r] * inv[i][r]);
  }
}

// ---------------------------------------------------------------------------
extern "C" void kernel_launch(void* const* d_in, const int* in_sizes, int n_in,
                              void* d_out, int out_size, void* d_ws, size_t ws_size,
                              hipStream_t stream) {
  const float* img = (const float*)d_in[0];
  const float* que = (const float*)d_in[1];
  const float* Wi  = (const float*)d_in[2];
  const float* bi  = (const float*)d_in[3];
  const float* Wq  = (const float*)d_in[4];
  const float* bq  = (const float*)d_in[5];
  const float* Wp  = (const float*)d_in[6];
  const float* bp  = (const float*)d_in[7];
  const int* mimg = (const int*)d_in[8];
  const int* mque = (const int*)d_in[9];
  float* out = (float*)d_out;

  // workspace carve (bf16 elements). Total = 224 MiB.
  // X1: img_bf16 during proj phase, reused as q2i after img-proj is done.
  // X2: que_bf16, reused as i2q.
  bf16* X1  = (bf16*)d_ws;         // 18874368 els
  bf16* X2  = X1 + 18874368;       //  8388608
  bf16* WiB = X2 + 8388608;        //  3145728
  bf16* WqB = WiB + 3145728;       //  3145728
  bf16* WpB = WqB + 3145728;       //  2097152
  bf16* PI  = WpB + 2097152;       // 3 x 18874368 (iq, ik, ivT)
  bf16* PQ  = PI + 56623104;       // 3 x  8388608 (qq, qk, qvT)

  cvt_bf16_multi<<<8192, 256, 0, stream>>>(img, X1, 18874368 / 4,
                                           que, X2, 8388608 / 4,
                                           Wi, WiB, 3145728 / 4,
                                           Wq, WqB, 3145728 / 4,
                                           Wp, WpB, 2097152 / 4);

  // merged QKV projections (N=3072; img rows y<72, que rows y>=72)
  gemm_bt<0><<<dim3(12, 104), 512, 0, stream>>>(X1, WiB, bi, PI, 576,
                                                X2, WqB, bq, PQ, 256, 72);

  const size_t SI = 18874368, SQ = 8388608;
  // merged attention: x<5 -> q2i = attn(iq, qk, qv, mask_que) -> X1;
  //                   x>=5 -> i2q = attn(qq, ik, iv, mask_img) -> X2
  attn<<<dim3(7, 512), 256, 0, stream>>>(PI, PQ + SQ, PQ + 2 * SQ, mque, X1, 576, 256, 5,
                                         PQ, PI + SI, PI + 2 * SI, mimg, X2, 256, 576);

  // merged output projections -> fp32 d_out (out0 then out1, concatenated)
  gemm_bt<1><<<dim3(4, 104), 512, 0, stream>>>(X1, WpB, bp, out, 0,
                                               X2, WpB + 1048576, bp + 1024, out + 18874368, 0, 72);
}

// Round 4
// 661.431 us; speedup vs baseline: 1.0155x; 1.0155x over previous
//
#include <hip/hip_runtime.h>

// MultiHeadedAttention cross-attention pipeline for MI355X (gfx950).
// B=32, N_img=576, L_q=256, D=1024, H=16, dk=64.
// Pipeline: cvt fp32->bf16 -> merged QKV proj GEMM (bf16 MFMA) -> merged flash
// attention -> merged output proj GEMM (fp32 out). 2% absmax tol allows bf16.
//
// R8: evidence: R4(128^2)/R6/R7(256^2 8-phase) all pin at ~2.4 TB/s L2-miss
// traffic with wildly different schedules -> GEMMs are traffic-bound, not
// MFMA-bound. Measured fetch ~4.5x ideal input bytes (XCD round-robin makes
// every block re-fetch its A/W panels; 8 non-coherent L2s).
// So: GEMM body reverted to R4's best-measured structure (128x128 tile,
// 256 thr, single-buffer 32 KiB LDS, ~3 blocks/CU, 935 TF, 0 conflicts),
// plus T1 XCD-chunked block swizzle: xcd = lid&7 owns a contiguous band of
// ny/8 m-rows, x-inner order -> each A row-panel fetched by exactly one XCD
// and reused by all x-blocks. ny = 208 for both merged GEMMs (208%8==0 ->
// bijective). Merged launches kept from R6 (QKV, out-proj, attn).

typedef __bf16 bf16;
typedef __attribute__((ext_vector_type(8))) __bf16 bf16x8;
typedef __attribute__((ext_vector_type(4))) __bf16 bf16x4;
typedef __attribute__((ext_vector_type(2))) __bf16 bf16x2;
typedef __attribute__((ext_vector_type(4))) float f32x4;

__device__ __forceinline__ void g2lds16(const void* g, void* l) {
  // async global->LDS, 16B/lane; LDS dest = wave-uniform base + lane*16
  __builtin_amdgcn_global_load_lds((const __attribute__((address_space(1))) void*)g,
                                   (__attribute__((address_space(3))) void*)l,
                                   16, 0, 0);
}

// ---------------------------------------------------------------------------
// fp32 -> bf16 conversion, all 5 tensors in one launch (float4 in, bf16x4 out)
// ---------------------------------------------------------------------------
__global__ void cvt_bf16_multi(const float* s0, bf16* d0, int n0,
                               const float* s1, bf16* d1, int n1,
                               const float* s2, bf16* d2, int n2,
                               const float* s3, bf16* d3, int n3,
                               const float* s4, bf16* d4, int n4c) {
  const int total = n0 + n1 + n2 + n3 + n4c;
  const int stride = gridDim.x * blockDim.x;
  for (int i = blockIdx.x * blockDim.x + threadIdx.x; i < total; i += stride) {
    int j = i;
    const float* s; bf16* d;
    if (j < n0) { s = s0; d = d0; }
    else { j -= n0;
      if (j < n1) { s = s1; d = d1; }
      else { j -= n1;
        if (j < n2) { s = s2; d = d2; }
        else { j -= n2;
          if (j < n3) { s = s3; d = d3; }
          else { j -= n3; s = s4; d = d4; }
        }
      }
    }
    const float4 v = ((const float4*)s)[j];
    bf16x4 o = {(bf16)v.x, (bf16)v.y, (bf16)v.z, (bf16)v.w};
    ((bf16x4*)d)[j] = o;
  }
}

// ---------------------------------------------------------------------------
// NT GEMM: C[m,e] = sum_d A[m,d]*W[e,d] + bias[e].  K=1024 fixed.
// 128x128 tile, BK=64, 256 threads (4 waves, each 64x64 = 4x4 MFMA tiles).
// R4 body (935 TF measured) + XCD-chunked swizzle + two-problem merge on the
// virtual y (ySplit boundary).
// LDS layout XOR-swizzled: slot (row, s) holds global k-chunk s^(row&7).
// MODE 0: proj epilogue -> bf16 head-split [p][B,H,L,64]; p==2 (V) transposed
//         to [B,H,64,L]. Lrow = L (576 or 256), N = 3072.
// MODE 1: final proj -> fp32 out[m*1024 + e], N = 1024.
// ---------------------------------------------------------------------------
template <int MODE>
__global__ __launch_bounds__(256, 2)
void gemm_bt(const bf16* __restrict__ A0, const bf16* __restrict__ W0,
             const float* __restrict__ bi0, void* __restrict__ o0, int L0,
             const bf16* __restrict__ A1, const bf16* __restrict__ W1,
             const float* __restrict__ bi1, void* __restrict__ o1, int L1,
             int ySplit) {
  __shared__ alignas(16) bf16 As[128 * 64];
  __shared__ alignas(16) bf16 Bs[128 * 64];
  const int tid = threadIdx.x;
  const int w = tid >> 6, lane = tid & 63;
  const int lr = lane & 15, quad = lane >> 4;
  const int i_q4 = quad * 4;

  // XCD-chunked swizzle: xcd = lid&7 owns vy in [xcd*ry, (xcd+1)*ry),
  // x-inner order (A-panel reuse within the XCD's L2). ny % 8 == 0.
  const int nx = (int)gridDim.x;
  const int lid = (int)blockIdx.y * nx + (int)blockIdx.x;
  const int xcd = lid & 7, s = lid >> 3;
  const int ry = (int)gridDim.y >> 3;
  const int sy = s / nx;
  const int vx = s - sy * nx;
  int vy = xcd * ry + sy;

  const bf16* A; const bf16* Bw; const float* bias; void* outp; int Lrow;
  if (vy < ySplit) { A = A0; Bw = W0; bias = bi0; outp = o0; Lrow = L0; }
  else { vy -= ySplit; A = A1; Bw = W1; bias = bi1; outp = o1; Lrow = L1; }
  const int mBase = vy * 128, nBase = vx * 128;
  const int wr = (w >> 1) * 64, wc = (w & 1) * 64;

  // staging: lane fetches global chunk (lane&7)^(row&7) so LDS ends up
  // swizzled; row = staged_base + (lane>>3), and staged_base % 8 == 0.
  const int swl = (((lane & 7) ^ ((lane >> 3) & 7)) * 8);
  const bf16* Ab = A + (size_t)(mBase + (lane >> 3)) * 1024 + swl;
  const bf16* Bb = Bw + (size_t)(nBase + (lane >> 3)) * 1024 + swl;

  f32x4 acc[4][4] = {};
  for (int kt = 0; kt < 16; ++kt) {
    const int k0 = kt * 64;
#pragma unroll
    for (int c = 0; c < 4; ++c) {
      const int rowOff = w * 32 + c * 8;  // wave-uniform
      g2lds16(Ab + (size_t)rowOff * 1024 + k0, As + rowOff * 64);
      g2lds16(Bb + (size_t)rowOff * 1024 + k0, Bs + rowOff * 64);
    }
    __syncthreads();
#pragma unroll
    for (int kk = 0; kk < 64; kk += 32) {
      // fragment chunk cg = quad | (kk/8); swizzled slot = cg ^ (row&7),
      // row&7 == lr&7 for all fragment rows (wr, i*16 are multiples of 8)
      const int sOff = ((quad | (kk >> 3)) ^ (lr & 7)) * 8;
      bf16x8 a[4], b[4];
#pragma unroll
      for (int i = 0; i < 4; ++i)
        a[i] = *(const bf16x8*)(As + (wr + i * 16 + lr) * 64 + sOff);
#pragma unroll
      for (int j = 0; j < 4; ++j)
        b[j] = *(const bf16x8*)(Bs + (wc + j * 16 + lr) * 64 + sOff);
#pragma unroll
      for (int i = 0; i < 4; ++i)
#pragma unroll
        for (int j = 0; j < 4; ++j)
          acc[i][j] = __builtin_amdgcn_mfma_f32_16x16x32_bf16(a[i], b[j], acc[i][j], 0, 0, 0);
    }
    __syncthreads();
  }

  // epilogue. C/D layout: col = lane&15, row = quad*4 + reg  [m89-verified]
  if constexpr (MODE == 1) {
    float* out = (float*)outp;
#pragma unroll
    for (int j = 0; j < 4; ++j) {
      const int e = nBase + wc + j * 16 + lr;
      const float bv = bias[e];
#pragma unroll
      for (int i = 0; i < 4; ++i) {
        const int mb = mBase + wr + i * 16 + i_q4;
#pragma unroll
        for (int r = 0; r < 4; ++r)
          out[(size_t)(mb + r) * 1024 + e] = acc[i][j][r] + bv;
      }
    }
  } else {
    bf16* out = (bf16*)outp;
    const int L = Lrow;
    const size_t slab = (size_t)512 * L * 64;  // one of iq/ik/iv
    int bb[4], ll[4];
#pragma unroll
    for (int i = 0; i < 4; ++i) {
      const int m = mBase + wr + i * 16 + i_q4;  // 4 consecutive rows share b (L%4==0)
      bb[i] = m / L;
      ll[i] = m - bb[i] * L;
    }
#pragma unroll
    for (int j = 0; j < 4; ++j) {
      const int eb = nBase + wc + j * 16;       // 16-aligned: p,h uniform per tile
      const int p = eb >> 10, h = (eb >> 6) & 15, d = (eb & 63) + lr;
      const float bv = bias[eb + lr];
      if (p < 2) {  // q/k: [B,H,L,64]
        bf16* o2 = out + (size_t)p * slab;
#pragma unroll
        for (int i = 0; i < 4; ++i) {
          bf16* o3 = o2 + ((size_t)(bb[i] * 16 + h) * L + ll[i]) * 64 + d;
#pragma unroll
          for (int r = 0; r < 4; ++r) o3[r * 64] = (bf16)(acc[i][j][r] + bv);
        }
      } else {      // v: transposed [B,H,64,L] so PV B-frag is contiguous
        bf16* o2 = out + 2 * slab;
#pragma unroll
        for (int i = 0; i < 4; ++i) {
          bf16x4 v;
#pragma unroll
          for (int r = 0; r < 4; ++r) v[r] = (bf16)(acc[i][j][r] + bv);
          *(bf16x4*)(o2 + ((size_t)(bb[i] * 16 + h) * 64 + d) * L + ll[i]) = v;
        }
      }
    }
  }
}

// ---------------------------------------------------------------------------
// Attention (two problems merged on blockIdx.x; xSplit boundary).
// Q:[B,H,Lq,64] K:[B,H,Lk,64] Vt:[B,H,64,Lk] (bf16), mask:[B,Lk] int
// (0 = masked), out:[B,Lq,H*64] bf16. 1 wave = 32 queries; K-tiles of 32.
// Fixed-shift softmax: p = exp2(s*log2e/8 + mb); masked keys mb=-1e9 -> p=0.
// Key->lane map interleaved (key = 2*lr + jn) so p-pairs pack to b32 writes.
// ---------------------------------------------------------------------------
#define PSTR 40
__global__ __launch_bounds__(256)
void attn(const bf16* __restrict__ Q0, const bf16* __restrict__ K0,
          const bf16* __restrict__ V0, const int* __restrict__ mk0,
          bf16* __restrict__ ou0, int Lq0, int Lk0, int xSplit,
          const bf16* __restrict__ Q1, const bf16* __restrict__ K1,
          const bf16* __restrict__ V1, const int* __restrict__ mk1,
          bf16* __restrict__ ou1, int Lq1, int Lk1) {
  __shared__ float mk[576];
  __shared__ alignas(16) bf16 pb[4][2][2][16 * PSTR];
  const int tid = threadIdx.x;
  const int w = tid >> 6, lane = tid & 63;
  const int lr = lane & 15, quad = lane >> 4, i_q4 = quad * 4;
  const int bh = blockIdx.y, b = bh >> 4, h = bh & 15;

  const bf16* Q; const bf16* K; const bf16* Vt; const int* mask; bf16* out;
  int Lq, Lk, gx = (int)blockIdx.x;
  if (gx < xSplit) { Q = Q0; K = K0; Vt = V0; mask = mk0; out = ou0; Lq = Lq0; Lk = Lk0; }
  else { gx -= xSplit; Q = Q1; K = K1; Vt = V1; mask = mk1; out = ou1; Lq = Lq1; Lk = Lk1; }
  const int q0 = gx * 128 + w * 32;

  for (int k = tid; k < Lk; k += 256)
    mk[k] = (mask[b * Lk + k] == 0) ? -1e9f : 0.0f;
  __syncthreads();
  if (q0 >= Lq) return;  // tail strips: whole idle waves (Lq % 32 == 0)

  // Q A-fragments: 2 m-tiles x 2 k-halves, held for the whole K loop
  bf16x8 qa[2][2];
#pragma unroll
  for (int i = 0; i < 2; ++i) {
    const bf16* Qb = Q + ((size_t)bh * Lq + q0 + i * 16 + lr) * 64 + quad * 8;
    qa[i][0] = *(const bf16x8*)(Qb);
    qa[i][1] = *(const bf16x8*)(Qb + 32);
  }
  const bf16* Kb = K + (size_t)bh * Lk * 64;
  const bf16* Vb = Vt + (size_t)bh * 64 * Lk;

  // K B-frag: key = kt*32 + 2*lr + jn (interleaved); V B-frag: k = quad*8+jj
  bf16x8 kc[2][2], kn[2][2], vc[4], vn[4];
  {
    const bf16* kp = Kb + (size_t)(lr * 2) * 64 + quad * 8;
    kc[0][0] = *(const bf16x8*)(kp);       kc[0][1] = *(const bf16x8*)(kp + 32);
    kc[1][0] = *(const bf16x8*)(kp + 64);  kc[1][1] = *(const bf16x8*)(kp + 96);
    const bf16* vp = Vb + quad * 8;
#pragma unroll
    for (int j = 0; j < 4; ++j) vc[j] = *(const bf16x8*)(vp + (size_t)(j * 16 + lr) * Lk);
  }

  f32x4 o[2][4] = {};
  float ls[2][4] = {};
  const int nkt = Lk >> 5;
  constexpr float SCL = 0.18033688f;  // log2(e)/8  (1/sqrt(dk) folded)
#pragma unroll 2
  for (int kt = 0; kt < nkt; ++kt) {
    // prefetch next tile (clamped; avoids reading past the slab)
    const int kp1 = (kt + 1 < nkt) ? kt + 1 : kt;
    {
      const bf16* kp = Kb + ((size_t)kp1 * 32 + lr * 2) * 64 + quad * 8;
      kn[0][0] = *(const bf16x8*)(kp);       kn[0][1] = *(const bf16x8*)(kp + 32);
      kn[1][0] = *(const bf16x8*)(kp + 64);  kn[1][1] = *(const bf16x8*)(kp + 96);
      const bf16* vp = Vb + kp1 * 32 + quad * 8;
#pragma unroll
      for (int j = 0; j < 4; ++j) vn[j] = *(const bf16x8*)(vp + (size_t)(j * 16 + lr) * Lk);
    }

    // scores: c[i][jn], C-layout col=lr -> key = kt*32 + 2*lr + jn
    f32x4 c[2][2];
#pragma unroll
    for (int i = 0; i < 2; ++i)
#pragma unroll
      for (int jn = 0; jn < 2; ++jn) {
        const f32x4 z = {};
        c[i][jn] = __builtin_amdgcn_mfma_f32_16x16x32_bf16(qa[i][0], kc[jn][0], z, 0, 0, 0);
        c[i][jn] = __builtin_amdgcn_mfma_f32_16x16x32_bf16(qa[i][1], kc[jn][1], c[i][jn], 0, 0, 0);
      }

    const float m0 = mk[kt * 32 + lr * 2], m1 = mk[kt * 32 + lr * 2 + 1];
#pragma unroll
    for (int i = 0; i < 2; ++i) {
      bf16* pw = &pb[w][kt & 1][i][0];
#pragma unroll
      for (int r = 0; r < 4; ++r) {
        const float p0 = __builtin_amdgcn_exp2f(__builtin_fmaf(c[i][0][r], SCL, m0));
        const float p1 = __builtin_amdgcn_exp2f(__builtin_fmaf(c[i][1][r], SCL, m1));
        ls[i][r] += p0 + p1;
        bf16x2 pp = {(bf16)p0, (bf16)p1};
        *(bf16x2*)(pw + (i_q4 + r) * PSTR + lr * 2) = pp;
      }
    }
    // P A-frag: P[m=lr][k=quad*8+jj], LDS col == key offset (interleaved map)
#pragma unroll
    for (int i = 0; i < 2; ++i) {
      const bf16x8 pa = *(const bf16x8*)(&pb[w][kt & 1][i][0] + lr * PSTR + quad * 8);
#pragma unroll
      for (int j = 0; j < 4; ++j)
        o[i][j] = __builtin_amdgcn_mfma_f32_16x16x32_bf16(pa, vc[j], o[i][j], 0, 0, 0);
    }
#pragma unroll
    for (int jn = 0; jn < 2; ++jn)
#pragma unroll
      for (int kh = 0; kh < 2; ++kh) kc[jn][kh] = kn[jn][kh];
#pragma unroll
    for (int j = 0; j < 4; ++j) vc[j] = vn[j];
  }

  // deferred l reduction (16 lanes of each quad hold disjoint key partials)
  float inv[2][4];
#pragma unroll
  for (int i = 0; i < 2; ++i)
#pragma unroll
    for (int r = 0; r < 4; ++r) {
      float s = ls[i][r];
#pragma unroll
      for (int off = 1; off < 16; off <<= 1) s += __shfl_xor(s, off);
      inv[i][r] = 1.0f / s;
    }

#pragma unroll
  for (int i = 0; i < 2; ++i) {
    bf16* ob = out + ((size_t)b * Lq + q0 + i * 16 + i_q4) * 1024 + h * 64;
#pragma unroll
    for (int j = 0; j < 4; ++j)
#pragma unroll
      for (int r = 0; r < 4; ++r)
        ob[(size_t)r * 1024 + j * 16 + lr] = (bf16)(o[i][j][r] * inv[i][r]);
  }
}

// ---------------------------------------------------------------------------
extern "C" void kernel_launch(void* const* d_in, const int* in_sizes, int n_in,
                              void* d_out, int out_size, void* d_ws, size_t ws_size,
                              hipStream_t stream) {
  const float* img = (const float*)d_in[0];
  const float* que = (const float*)d_in[1];
  const float* Wi  = (const float*)d_in[2];
  const float* bi  = (const float*)d_in[3];
  const float* Wq  = (const float*)d_in[4];
  const float* bq  = (const float*)d_in[5];
  const float* Wp  = (const float*)d_in[6];
  const float* bp  = (const float*)d_in[7];
  const int* mimg = (const int*)d_in[8];
  const int* mque = (const int*)d_in[9];
  float* out = (float*)d_out;

  // workspace carve (bf16 elements). Total = 224 MiB.
  // X1: img_bf16 during proj phase, reused as q2i after img-proj is done.
  // X2: que_bf16, reused as i2q.
  bf16* X1  = (bf16*)d_ws;         // 18874368 els
  bf16* X2  = X1 + 18874368;       //  8388608
  bf16* WiB = X2 + 8388608;        //  3145728
  bf16* WqB = WiB + 3145728;       //  3145728
  bf16* WpB = WqB + 3145728;       //  2097152
  bf16* PI  = WpB + 2097152;       // 3 x 18874368 (iq, ik, ivT)
  bf16* PQ  = PI + 56623104;       // 3 x  8388608 (qq, qk, qvT)

  cvt_bf16_multi<<<8192, 256, 0, stream>>>(img, X1, 18874368 / 4,
                                           que, X2, 8388608 / 4,
                                           Wi, WiB, 3145728 / 4,
                                           Wq, WqB, 3145728 / 4,
                                           Wp, WpB, 2097152 / 4);

  // merged QKV projections, 128^2 tiles: img rows vy<144, que rows vy>=144
  gemm_bt<0><<<dim3(24, 208), 256, 0, stream>>>(X1, WiB, bi, PI, 576,
                                                X2, WqB, bq, PQ, 256, 144);

  const size_t SI = 18874368, SQ = 8388608;
  // merged attention: x<5 -> q2i = attn(iq, qk, qv, mask_que) -> X1;
  //                   x>=5 -> i2q = attn(qq, ik, iv, mask_img) -> X2
  attn<<<dim3(7, 512), 256, 0, stream>>>(PI, PQ + SQ, PQ + 2 * SQ, mque, X1, 576, 256, 5,
                                         PQ, PI + SI, PI + 2 * SI, mimg, X2, 256, 576);

  // merged output projections -> fp32 d_out (out0 then out1, concatenated)
  gemm_bt<1><<<dim3(8, 208), 256, 0, stream>>>(X1, WpB, bp, out, 0,
                                               X2, WpB + 1048576, bp + 1024, out + 18874368, 0, 144);
}